// Round 2
// baseline (622.412 us; speedup 1.0000x reference)
//
#include <hip/hip_runtime.h>
#include <hip/hip_bf16.h>

typedef __bf16 bf16;
typedef bf16 bf16x4 __attribute__((ext_vector_type(4)));
typedef bf16 bf16x8 __attribute__((ext_vector_type(8)));
typedef float f32x4 __attribute__((ext_vector_type(4)));

#define MFMA16(a, b, c) __builtin_amdgcn_mfma_f32_16x16x32_bf16((a), (b), (c), 0, 0, 0)

constexpr int kN = 49, kC = 256;
constexpr float kScale = 0.17677669529663687f;  // 1/sqrt(32)

// ---- workspace offsets (bytes) ----
constexpr int WQKV_OFF = 0;        // bf16[768*256]
constexpr int WPROJ_OFF = 393216;  // bf16[256*256]
constexpr int BIAS_OFF = 524288;   // f32[8*49*49]
constexpr int BQKV_OFF = 601120;   // f32[768]

// ---- LDS offsets (bytes) ----
constexpr int XB_OFF = 0;        // bf16 [32 cc][64 n][8]  (x, later attn-out)
constexpr int QK_OFF = 32768;    // bf16 [64 oc][56 n][8]  (Q rows o<256 scaled, K rows 256..511)
constexpr int VT_OFF = 90112;    // bf16 [8 h][8 mc][32 d][8]  (V transposed)
constexpr int PT_OFF = 122880;   // per-wave 8192 B: bf16 [4 rt][16 nlow][64 m]
constexpr int LDS_BYTES = 155648;

__global__ void prep_kernel(const float* __restrict__ w_qkv, const float* __restrict__ b_qkv,
                            const float* __restrict__ w_proj, const float* __restrict__ bias_table,
                            const int* __restrict__ rel_index, char* __restrict__ ws) {
  int i = blockIdx.x * 256 + threadIdx.x;
  bf16* wqkvb = (bf16*)(ws + WQKV_OFF);
  bf16* wprojb = (bf16*)(ws + WPROJ_OFF);
  float* biasx = (float*)(ws + BIAS_OFF);
  float* bqs = (float*)(ws + BQKV_OFF);
  if (i < 196608) {
    float v = w_qkv[i];
    if (i < 65536) v *= kScale;  // q rows (o<256): fold scale
    wqkvb[i] = (bf16)v;
  } else if (i < 262144) {
    int j = i - 196608;
    wprojb[j] = (bf16)w_proj[j];
  } else if (i < 281352) {
    int j = i - 262144;  // 8*2401
    int h = j / 2401, nm = j - h * 2401;
    biasx[j] = bias_table[rel_index[nm] * 8 + h];
  } else if (i < 282120) {
    int j = i - 281352;
    bqs[j] = b_qkv[j] * (j < 256 ? kScale : 1.0f);
  }
}

__global__ __launch_bounds__(256, 1) void attn_kernel(
    const float* __restrict__ x, const float* __restrict__ mask, const float* __restrict__ b_proj,
    const char* __restrict__ ws, float* __restrict__ out) {
  extern __shared__ char smem[];
  bf16* xb = (bf16*)(smem + XB_OFF);
  bf16* qk = (bf16*)(smem + QK_OFF);
  bf16* vt = (bf16*)(smem + VT_OFF);

  const bf16* wqkvb = (const bf16*)(ws + WQKV_OFF);
  const bf16* wprojb = (const bf16*)(ws + WPROJ_OFF);
  const float* biasx = (const float*)(ws + BIAS_OFF);
  const float* bqs = (const float*)(ws + BQKV_OFF);

  const int tid = threadIdx.x;
  const int w = blockIdx.x;
  const int lane = tid & 63;
  const int wave = tid >> 6;
  const int g = lane >> 4;   // 16-lane group
  const int c = lane & 15;

  const float* xw = x + (size_t)w * (kN * kC);

  // ---- stage x -> xb bf16, chunked [cc=ch/8][n][ch&7]; zero pad rows 49..63 ----
#pragma unroll
  for (int it = 0; it < 13; ++it) {
    int idx = it * 256 + tid;  // over 49*64 float4 units
    if (idx < 3136) {
      int n = idx >> 6, c4 = (idx & 63) << 2;
      float4 v = ((const float4*)xw)[idx];
      bf16x4 b4;
      b4[0] = (bf16)v.x; b4[1] = (bf16)v.y; b4[2] = (bf16)v.z; b4[3] = (bf16)v.w;
      *(bf16x4*)(xb + ((c4 >> 3) * 512 + n * 8 + (c4 & 7))) = b4;
    }
  }
#pragma unroll
  for (int it = 0; it < 4; ++it) {
    int idx = it * 256 + tid;
    if (idx < 960) {
      int n = 49 + (idx >> 6), c4 = (idx & 63) << 2;
      *(unsigned long long*)(xb + ((c4 >> 3) * 512 + n * 8 + (c4 & 7))) = 0ULL;
    }
  }
  __syncthreads();

  // ---- sub-GEMM1: Q,K.  D[o][n] = sum_c W[o][c]*X[n][c].  wave owns 8 o-tiles ----
  for (int t = 0; t < 8; ++t) {
    int ot = wave * 8 + t;
    const bf16* ab = wqkvb + (ot * 16 + c) * 256 + g * 8;  // A row o = l&15, k contig
    bf16x8 afr[8];
#pragma unroll
    for (int ks = 0; ks < 8; ++ks) afr[ks] = *(const bf16x8*)(ab + ks * 32);
    f32x4 acc[4] = {};
#pragma unroll
    for (int ks = 0; ks < 8; ++ks) {
      const bf16* bb = xb + (ks * 4 + g) * 512 + c * 8;  // B col n = l&15
#pragma unroll
      for (int nt = 0; nt < 4; ++nt) {
        bf16x8 bfr = *(const bf16x8*)(bb + nt * 128);
        acc[nt] = MFMA16(afr[ks], bfr, acc[nt]);
      }
    }
    int ob = ot * 16 + g * 4;
    float bq0 = bqs[ob], bq1 = bqs[ob + 1], bq2 = bqs[ob + 2], bq3 = bqs[ob + 3];
    int oc = ob >> 3, olow = ob & 7;
#pragma unroll
    for (int nt = 0; nt < 4; ++nt) {
      int n = nt * 16 + c;
      if (n < 56) {
        bool ok = (n < 49);
        bf16x4 pk;
        pk[0] = ok ? (bf16)(acc[nt][0] + bq0) : (bf16)0.f;
        pk[1] = ok ? (bf16)(acc[nt][1] + bq1) : (bf16)0.f;
        pk[2] = ok ? (bf16)(acc[nt][2] + bq2) : (bf16)0.f;
        pk[3] = ok ? (bf16)(acc[nt][3] + bq3) : (bf16)0.f;
        *(bf16x4*)(qk + (oc * 448 + n * 8 + olow)) = pk;
      }
    }
  }

  // ---- sub-GEMM2: V.  D[n][o] = sum_c X[n][c]*W[o][c] -> vt[h][m/8][d][m&7] ----
  for (int t = 0; t < 4; ++t) {
    int ct = wave * 4 + t;
    int o = 512 + ct * 16 + c;
    const bf16* bb = wqkvb + o * 256 + g * 8;
    bf16x8 bfr[8];
#pragma unroll
    for (int ks = 0; ks < 8; ++ks) bfr[ks] = *(const bf16x8*)(bb + ks * 32);
    f32x4 acc[4] = {};
#pragma unroll
    for (int ks = 0; ks < 8; ++ks) {
      const bf16* abL = xb + (ks * 4 + g) * 512 + c * 8;
#pragma unroll
      for (int mt = 0; mt < 4; ++mt) {
        bf16x8 afr = *(const bf16x8*)(abL + mt * 128);
        acc[mt] = MFMA16(afr, bfr[ks], acc[mt]);
      }
    }
    float bv = bqs[o];
    int h = ct >> 1;
    int d = (ct * 16 + c) & 31;
#pragma unroll
    for (int mt = 0; mt < 4; ++mt) {
      int mb = mt * 16 + g * 4;
      bf16x4 pk;
      pk[0] = (bf16)(acc[mt][0] + bv); pk[1] = (bf16)(acc[mt][1] + bv);
      pk[2] = (bf16)(acc[mt][2] + bv); pk[3] = (bf16)(acc[mt][3] + bv);
      *(bf16x4*)(vt + (h * 2048 + (mb >> 3) * 256 + d * 8 + (mb & 7))) = pk;
    }
  }
  __syncthreads();

  // ---- attention: wave handles heads 2w, 2w+1 ----
  bf16* ptp = (bf16*)(smem + PT_OFF + wave * 8192);  // [4 rt][16 nlow][64 m]
  const float* mk = mask + (size_t)w * 2401;

  for (int hh = 0; hh < 2; ++hh) {
    int h = wave * 2 + hh;
    // QK^T: S[n][m], 16 MFMAs, all in regs
    bf16x8 qa[4], kb[4];
#pragma unroll
    for (int rt = 0; rt < 4; ++rt)
      qa[rt] = *(const bf16x8*)(qk + ((h * 4 + g) * 448 + (rt * 16 + c) * 8));
#pragma unroll
    for (int mt = 0; mt < 4; ++mt)
      kb[mt] = *(const bf16x8*)(qk + ((32 + h * 4 + g) * 448 + (mt * 16 + c) * 8));
    f32x4 s[4][4] = {};
#pragma unroll
    for (int rt = 0; rt < 4; ++rt)
#pragma unroll
      for (int mt = 0; mt < 4; ++mt) s[rt][mt] = MFMA16(qa[rt], kb[mt], s[rt][mt]);

    const float* bh = biasx + h * 2401;
#pragma unroll
    for (int rt = 0; rt < 4; ++rt) {
      float pk_[4][4];  // [mt][i]
#pragma unroll
      for (int i = 0; i < 4; ++i) {
        int n = rt * 16 + g * 4 + i;
        bool nok = (n < 49);
        float vals[4];
#pragma unroll
        for (int mt = 0; mt < 4; ++mt) {
          int m = mt * 16 + c;
          float v = -1e30f;
          if (nok && m < 49) v = s[rt][mt][i] + bh[n * 49 + m] + mk[n * 49 + m];
          vals[mt] = v;
        }
        float mx = fmaxf(fmaxf(vals[0], vals[1]), fmaxf(vals[2], vals[3]));
        mx = fmaxf(mx, __shfl_xor(mx, 1));
        mx = fmaxf(mx, __shfl_xor(mx, 2));
        mx = fmaxf(mx, __shfl_xor(mx, 4));
        mx = fmaxf(mx, __shfl_xor(mx, 8));
        float p0 = __expf(vals[0] - mx), p1 = __expf(vals[1] - mx);
        float p2 = __expf(vals[2] - mx), p3 = __expf(vals[3] - mx);
        float sum = p0 + p1 + p2 + p3;
        sum += __shfl_xor(sum, 1);
        sum += __shfl_xor(sum, 2);
        sum += __shfl_xor(sum, 4);
        sum += __shfl_xor(sum, 8);
        float rinv = 1.0f / sum;
        pk_[0][i] = p0 * rinv; pk_[1][i] = p1 * rinv;
        pk_[2][i] = p2 * rinv; pk_[3][i] = p3 * rinv;
      }
      // scatter-store P: pl[rt][nlow][m] = P[n = rt*16+nlow][m]  (m-contiguous layout)
#pragma unroll
      for (int mt = 0; mt < 4; ++mt) {
        int m = mt * 16 + c;
#pragma unroll
        for (int i = 0; i < 4; ++i) {
          ptp[rt * 1024 + (g * 4 + i) * 64 + m] = (bf16)pk_[mt][i];
        }
      }
    }
    asm volatile("s_waitcnt lgkmcnt(0)" ::: "memory");  // P visible before reads (same wave)

    // PV^T: out^T[d][n] = sum_m V^T[d][m] * P^T[m][n]
    bf16x8 va[2][2];
#pragma unroll
    for (int dt = 0; dt < 2; ++dt)
#pragma unroll
      for (int ks = 0; ks < 2; ++ks)
        va[dt][ks] = *(const bf16x8*)(vt + (h * 2048 + (ks * 4 + g) * 256 + (dt * 16 + c) * 8));
    f32x4 oacc[2][4] = {};
#pragma unroll
    for (int nt = 0; nt < 4; ++nt) {
      const bf16* pr = ptp + nt * 1024 + c * 64 + g * 8;  // B[k=m][col=nlow=c]
      bf16x8 pb0 = *(const bf16x8*)(pr);        // m = g*8+j
      bf16x8 pb1 = *(const bf16x8*)(pr + 32);   // m = 32+g*8+j
#pragma unroll
      for (int dt = 0; dt < 2; ++dt) {
        oacc[dt][nt] = MFMA16(va[dt][0], pb0, oacc[dt][nt]);
        oacc[dt][nt] = MFMA16(va[dt][1], pb1, oacc[dt][nt]);
      }
    }
    // attn-out -> xb buffer (xb dead after sub-GEMMs)
#pragma unroll
    for (int dt = 0; dt < 2; ++dt) {
      int cb = h * 32 + dt * 16 + g * 4;
      int cc = cb >> 3, clow = cb & 7;
#pragma unroll
      for (int nt = 0; nt < 4; ++nt) {
        int n = nt * 16 + c;
        bf16x4 pk;
        pk[0] = (bf16)oacc[dt][nt][0]; pk[1] = (bf16)oacc[dt][nt][1];
        pk[2] = (bf16)oacc[dt][nt][2]; pk[3] = (bf16)oacc[dt][nt][3];
        *(bf16x4*)(xb + (cc * 512 + n * 8 + clow)) = pk;
      }
    }
  }
  __syncthreads();

  // ---- proj: out[n][co] = sum_c ao[n][c]*Wp[co][c] + bp ----
  float* outw = out + (size_t)w * (kN * kC);
  for (int t = 0; t < 4; ++t) {
    int ct = wave * 4 + t;
    const bf16* bb = wprojb + (ct * 16 + c) * 256 + g * 8;
    bf16x8 bfr[8];
#pragma unroll
    for (int ks = 0; ks < 8; ++ks) bfr[ks] = *(const bf16x8*)(bb + ks * 32);
    f32x4 acc[4] = {};
#pragma unroll
    for (int ks = 0; ks < 8; ++ks) {
      const bf16* abL = xb + (ks * 4 + g) * 512 + c * 8;
#pragma unroll
      for (int mt = 0; mt < 4; ++mt) {
        bf16x8 afr = *(const bf16x8*)(abL + mt * 128);
        acc[mt] = MFMA16(afr, bfr[ks], acc[mt]);
      }
    }
    float bp = b_proj[ct * 16 + c];
#pragma unroll
    for (int mt = 0; mt < 4; ++mt) {
#pragma unroll
      for (int i = 0; i < 4; ++i) {
        int n = mt * 16 + g * 4 + i;
        if (n < 49) outw[n * 256 + ct * 16 + c] = acc[mt][i] + bp;
      }
    }
  }
}

extern "C" void kernel_launch(void* const* d_in, const int* in_sizes, int n_in,
                              void* d_out, int out_size, void* d_ws, size_t ws_size,
                              hipStream_t stream) {
  const float* x = (const float*)d_in[0];
  const float* mask = (const float*)d_in[1];
  const float* w_qkv = (const float*)d_in[2];
  const float* b_qkv = (const float*)d_in[3];
  const float* w_proj = (const float*)d_in[4];
  const float* b_proj = (const float*)d_in[5];
  const float* bias_table = (const float*)d_in[6];
  const int* rel_index = (const int*)d_in[7];
  float* out = (float*)d_out;
  char* ws = (char*)d_ws;

  (void)in_sizes; (void)n_in; (void)out_size; (void)ws_size;

  hipFuncSetAttribute((const void*)attn_kernel, hipFuncAttributeMaxDynamicSharedMemorySize,
                      LDS_BYTES);

  prep_kernel<<<1103, 256, 0, stream>>>(w_qkv, b_qkv, w_proj, bias_table, rel_index, ws);
  attn_kernel<<<4096, 256, LDS_BYTES, stream>>>(x, mask, b_proj, ws, out);
}